// Round 2
// baseline (566.401 us; speedup 1.0000x reference)
//
#include <hip/hip_runtime.h>
#include <stdint.h>

#define N_NODES   50000
#define N_EDGES   400000
#define IN_FEATS  16
#define HIDDEN    32
#define K1        128      // EDGE_MLP_HID
#define NOUT      512      // IN_FEATS*HIDDEN
#define N_CLS     100000
#define TILE_E    64
#define N_TILES   (N_EDGES / TILE_E)   // 6250
#define FUSED_GRID 2048

typedef float  f32x4  __attribute__((ext_vector_type(4)));
typedef __bf16 bf16x8 __attribute__((ext_vector_type(8)));

__device__ __forceinline__ unsigned short f32_bf16(float f) {
    union { float f; uint32_t u; } c; c.f = f;
    uint32_t r = c.u + 0x7fffu + ((c.u >> 16) & 1u);
    return (unsigned short)(r >> 16);
}

// ---- prep: W2 [128,512] -> W2T bf16 [512,128]; W1 [16,128] -> W1T bf16 [128,32] (K padded) ----
__global__ void prep_weights(const float* __restrict__ w2, const float* __restrict__ w1,
                             unsigned short* __restrict__ w2t, unsigned short* __restrict__ w1t) {
    int tid = blockIdx.x * 256 + threadIdx.x;
    if (tid < NOUT * K1) {
        int n = tid >> 7, k = tid & 127;
        w2t[n * 128 + k] = f32_bf16(w2[k * 512 + n]);
    } else {
        int t = tid - NOUT * K1;            // [0, 4096)
        int n = t >> 5, k = t & 31;
        w1t[n * 32 + k] = (k < 16) ? f32_bf16(w1[k * 128 + n]) : (unsigned short)0;
    }
}

__global__ void zero_f32v4(float4* __restrict__ p, int n4) {
    int i = blockIdx.x * 256 + threadIdx.x;
    if (i < n4) { float4 z = {0.f, 0.f, 0.f, 0.f}; p[i] = z; }
}

// ---- fused: edge MLP (MFMA, B in registers) + per-edge matvec + scatter-add ----
__global__ __launch_bounds__(256, 2) void fused_msg(
    const float* __restrict__ nf, const float* __restrict__ ef,
    const int* __restrict__ src, const int* __restrict__ dst,
    const unsigned short* __restrict__ w1t, const float* __restrict__ b1,
    const unsigned short* __restrict__ w2t, const float* __restrict__ b2,
    float* __restrict__ agg, float* __restrict__ deg)
{
    __shared__ __align__(16) unsigned short sW1T[128 * 32];   // [n][k] swizzled, 8KB
    __shared__ __align__(16) unsigned short sAef[64 * 32];    // edge feats bf16, K padded, swizzled, 4KB
    __shared__ __align__(16) unsigned short sA[64 * 128];     // relu1 bf16, swizzled, 16KB
    __shared__ __align__(16) float sX[64 * 16];               // gathered src node feats, 4KB
    __shared__ __align__(16) float sPart[64 * 32];            // msg partials (XOR-swizzled h), 8KB
    __shared__ int   sSrc[64], sDst[64];

    const int tid  = threadIdx.x;
    const int lane = tid & 63;
    const int w    = tid >> 6;      // wave 0..3 = output-column chunk
    const int l15  = lane & 15;
    const int lg   = lane >> 4;     // 0..3

    // ---- per-block setup: B chunk (128 cols x 128 k) resident in VGPRs ----
    bf16x8 bReg[8][4];
    #pragma unroll
    for (int f = 0; f < 8; ++f)
        #pragma unroll
        for (int kb = 0; kb < 4; ++kb)
            bReg[f][kb] = *reinterpret_cast<const bf16x8*>(
                &w2t[(w * 128 + f * 16 + l15) * 128 + kb * 32 + lg * 8]);

    float b1v[8], b2v[8];
    #pragma unroll
    for (int f = 0; f < 8; ++f) {
        b1v[f] = b1[f * 16 + l15];
        b2v[f] = b2[w * 128 + f * 16 + l15];
    }

    // stage W1T once per block (4096 bf16), swizzle k ^= (n&3)<<3
    #pragma unroll
    for (int p = 0; p < 2; ++p) {
        int idx = p * 2048 + tid * 8;
        int n = idx >> 5, k0 = idx & 31;
        uint4 v = *reinterpret_cast<const uint4*>(&w1t[idx]);
        *reinterpret_cast<uint4*>(&sW1T[n * 32 + (k0 ^ ((n & 3) << 3))]) = v;
    }

    for (int tile = blockIdx.x; tile < N_TILES; tile += FUSED_GRID) {
        const int e0 = tile * TILE_E;

        // ---------- phase 1: stage indices + edge feats, zero sPart ----------
        if (tid < 64) { sSrc[tid] = src[e0 + tid]; sDst[tid] = dst[e0 + tid]; }
        {
            int idx = tid * 8;
            int e = idx >> 5, k0 = idx & 31;
            unsigned short tmp[8];
            if (k0 < 16) {
                float4 f0 = *reinterpret_cast<const float4*>(&ef[(e0 + e) * 16 + k0]);
                float4 f1 = *reinterpret_cast<const float4*>(&ef[(e0 + e) * 16 + k0 + 4]);
                tmp[0] = f32_bf16(f0.x); tmp[1] = f32_bf16(f0.y); tmp[2] = f32_bf16(f0.z); tmp[3] = f32_bf16(f0.w);
                tmp[4] = f32_bf16(f1.x); tmp[5] = f32_bf16(f1.y); tmp[6] = f32_bf16(f1.z); tmp[7] = f32_bf16(f1.w);
            } else {
                #pragma unroll
                for (int j = 0; j < 8; ++j) tmp[j] = 0;
            }
            *reinterpret_cast<uint4*>(&sAef[e * 32 + (k0 ^ ((e & 3) << 3))]) = *reinterpret_cast<const uint4*>(tmp);
        }
        {
            float4 z = {0.f, 0.f, 0.f, 0.f};
            #pragma unroll
            for (int p = 0; p < 2; ++p)
                *reinterpret_cast<float4*>(&sPart[(p * 256 + tid) * 4]) = z;
        }
        __syncthreads();

        // ---------- phase 2: gather src feats, deg atomics, layer-1 MFMA ----------
        {
            int e = tid >> 2, q = tid & 3;
            float4 v = *reinterpret_cast<const float4*>(&nf[sSrc[e] * 16 + q * 4]);
            *reinterpret_cast<float4*>(&sX[e * 16 + q * 4]) = v;
        }
        if (tid < 64) atomicAdd(&deg[sDst[tid]], 1.0f);
        {
            int row = w * 16 + l15;
            bf16x8 a = *reinterpret_cast<const bf16x8*>(&sAef[row * 32 + ((lg * 8) ^ ((row & 3) << 3))]);
            #pragma unroll
            for (int f = 0; f < 8; ++f) {
                int n = f * 16 + l15;
                bf16x8 b = *reinterpret_cast<const bf16x8*>(&sW1T[n * 32 + ((lg * 8) ^ ((n & 3) << 3))]);
                f32x4 c = { b1v[f], b1v[f], b1v[f], b1v[f] };
                c = __builtin_amdgcn_mfma_f32_16x16x32_bf16(a, b, c, 0, 0, 0);
                #pragma unroll
                for (int r = 0; r < 4; ++r) {
                    int e = w * 16 + lg * 4 + r;   // C row = (lane>>4)*4 + reg
                    sA[e * 128 + (n ^ ((e & 7) << 3))] = f32_bf16(fmaxf(c[r], 0.0f));
                }
            }
        }
        __syncthreads();

        // ---------- phase 3: layer-2 (B resident), fused msg partials -> sPart ----------
        #pragma unroll
        for (int rt = 0; rt < 4; ++rt) {
            int row = rt * 16 + l15;
            f32x4 acc[8];
            #pragma unroll
            for (int f = 0; f < 8; ++f) { f32x4 c = {b2v[f], b2v[f], b2v[f], b2v[f]}; acc[f] = c; }
            #pragma unroll
            for (int kb = 0; kb < 4; ++kb) {
                bf16x8 a = *reinterpret_cast<const bf16x8*>(
                    &sA[row * 128 + ((kb * 32 + lg * 8) ^ ((row & 7) << 3))]);
                #pragma unroll
                for (int f = 0; f < 8; ++f)
                    acc[f] = __builtin_amdgcn_mfma_f32_16x16x32_bf16(a, bReg[f][kb], acc[f], 0, 0, 0);
            }
            // epilogue: msg[e][h] partial over this wave's 4 i-values (i = w*4 + f>>1)
            int swh = (lg & 1) << 4;   // == ((e>>2)&1)<<4 for e below
            #pragma unroll
            for (int r = 0; r < 4; ++r) {
                int e = rt * 16 + lg * 4 + r;
                float4 xv = *reinterpret_cast<const float4*>(&sX[e * 16 + w * 4]);
                float xa[4] = { xv.x, xv.y, xv.z, xv.w };
                float m0 = 0.f, m1 = 0.f;
                #pragma unroll
                for (int f = 0; f < 8; ++f) {
                    float t = xa[f >> 1] * acc[f][r];
                    if (f & 1) m1 += t; else m0 += t;
                }
                atomicAdd(&sPart[e * 32 + (l15 ^ swh)], m0);
                atomicAdd(&sPart[e * 32 + ((16 + l15) ^ swh)], m1);
            }
        }
        __syncthreads();

        // ---------- phase 4: scatter to agg ----------
        #pragma unroll
        for (int k = 0; k < 8; ++k) {
            int idx = tid + k * 256;
            int e = idx >> 5, hh = idx & 31;
            float val = sPart[e * 32 + (hh ^ (((e >> 2) & 1) << 4))];
            atomicAdd(&agg[sDst[e] * 32 + hh], val);
        }
        __syncthreads();
    }
}

// ---- h = relu(agg/max(deg,1) + conv_b), float4 ----
__global__ void finalize_h(const float* __restrict__ agg, const float* __restrict__ deg,
                           const float* __restrict__ conv_b, float* __restrict__ h) {
    int t = blockIdx.x * 256 + threadIdx.x;
    if (t >= N_NODES * 8) return;
    int v = t >> 3, f0 = (t & 7) * 4;
    float d = fmaxf(deg[v], 1.0f);
    float4 a  = *reinterpret_cast<const float4*>(&agg[t * 4]);
    float4 cb = *reinterpret_cast<const float4*>(&conv_b[f0]);
    float4 o;
    o.x = fmaxf(a.x / d + cb.x, 0.f);
    o.y = fmaxf(a.y / d + cb.y, 0.f);
    o.z = fmaxf(a.z / d + cb.z, 0.f);
    o.w = fmaxf(a.w / d + cb.w, 0.f);
    *reinterpret_cast<float4*>(&h[t * 4]) = o;
}

// ---- classifier: 32 edges per 256-thread block ----
__global__ __launch_bounds__(256) void classifier(
    const float* __restrict__ h, const float* __restrict__ ef,
    const int* __restrict__ src, const int* __restrict__ dst, const int* __restrict__ eidx,
    const float* __restrict__ w1, const float* __restrict__ b1,
    const float* __restrict__ w2, const float* __restrict__ b2, float* __restrict__ out)
{
    __shared__ float sIn[32][84];
    __shared__ float sW1[80 * 32];
    __shared__ float sHid[32][36];
    __shared__ int   sE[32 * 3];
    int tid = threadIdx.x;
    int eb  = blockIdx.x * 32;

    for (int i = tid; i < 640; i += 256)
        *reinterpret_cast<float4*>(&sW1[i * 4]) = *reinterpret_cast<const float4*>(&w1[i * 4]);
    if (tid < 32) {
        int ei = eidx[eb + tid];
        sE[tid * 3 + 0] = ei;
        sE[tid * 3 + 1] = src[ei];
        sE[tid * 3 + 2] = dst[ei];
    }
    __syncthreads();
    {
        int e = tid >> 3, l8 = tid & 7;
        int ei = sE[e * 3 + 0], sn = sE[e * 3 + 1], dn = sE[e * 3 + 2];
        #pragma unroll
        for (int j = 0; j < 10; ++j) {
            int c = l8 + j * 8;
            float v;
            if (c < 32)      v = h[sn * 32 + c];
            else if (c < 64) v = h[dn * 32 + (c - 32)];
            else             v = ef[ei * 16 + (c - 64)];
            sIn[e][c] = v;
        }
    }
    __syncthreads();
    {
        int e = tid >> 3, j0 = (tid & 7) * 4;
        float4 acc = *reinterpret_cast<const float4*>(&b1[j0]);
        #pragma unroll 8
        for (int k = 0; k < 80; ++k) {
            float x = sIn[e][k];
            float4 wv = *reinterpret_cast<const float4*>(&sW1[k * 32 + j0]);
            acc.x += x * wv.x; acc.y += x * wv.y; acc.z += x * wv.z; acc.w += x * wv.w;
        }
        sHid[e][j0 + 0] = fmaxf(acc.x, 0.f);
        sHid[e][j0 + 1] = fmaxf(acc.y, 0.f);
        sHid[e][j0 + 2] = fmaxf(acc.z, 0.f);
        sHid[e][j0 + 3] = fmaxf(acc.w, 0.f);
    }
    __syncthreads();
    if (tid < 64) {
        int e = tid >> 1, o = tid & 1;
        float acc = b2[o];
        #pragma unroll
        for (int j = 0; j < 32; ++j) acc += sHid[e][j] * w2[j * 2 + o];
        out[(eb + e) * 2 + o] = acc;
    }
}

extern "C" void kernel_launch(void* const* d_in, const int* in_sizes, int n_in,
                              void* d_out, int out_size, void* d_ws, size_t ws_size,
                              hipStream_t stream) {
    const float* nf     = (const float*)d_in[0];
    const float* ef     = (const float*)d_in[1];
    const int*   src    = (const int*)d_in[2];
    const int*   dst    = (const int*)d_in[3];
    const int*   eidx   = (const int*)d_in[4];
    const float* en_w1  = (const float*)d_in[5];
    const float* en_b1  = (const float*)d_in[6];
    const float* en_w2  = (const float*)d_in[7];
    const float* en_b2  = (const float*)d_in[8];
    const float* conv_b = (const float*)d_in[9];
    const float* cls_w1 = (const float*)d_in[10];
    const float* cls_b1 = (const float*)d_in[11];
    const float* cls_w2 = (const float*)d_in[12];
    const float* cls_b2 = (const float*)d_in[13];
    float* out = (float*)d_out;

    char* ws = (char*)d_ws;
    unsigned short* w2t = (unsigned short*)(ws);               // 131072 B
    unsigned short* w1t = (unsigned short*)(ws + 131072);      // 8192 B
    float* agg = (float*)(ws + 139264);                        // 6,400,000 B
    float* deg = (float*)(ws + 139264 + 6400000);              // 200,000 B
    float* h   = (float*)(ws + 139264 + 6600000);              // 6,400,000 B

    // zero agg+deg (contiguous 1,650,000 floats = 412,500 float4)
    zero_f32v4<<<(412500 + 255) / 256, 256, 0, stream>>>((float4*)agg, 412500);
    prep_weights<<<(NOUT * K1 + 4096) / 256, 256, 0, stream>>>(en_w2, en_w1, w2t, w1t);
    fused_msg<<<FUSED_GRID, 256, 0, stream>>>(nf, ef, src, dst, w1t, en_b1, w2t, en_b2, agg, deg);
    finalize_h<<<(N_NODES * 8 + 255) / 256, 256, 0, stream>>>(agg, deg, conv_b, h);
    classifier<<<N_CLS / 32, 256, 0, stream>>>(h, ef, src, dst, eidx, cls_w1, cls_b1, cls_w2, cls_b2, out);
}

// Round 3
// 399.554 us; speedup vs baseline: 1.4176x; 1.4176x over previous
//
#include <hip/hip_runtime.h>
#include <stdint.h>

#define N_NODES   50000
#define N_EDGES   400000
#define IN_FEATS  16
#define HIDDEN    32
#define K1        128      // EDGE_MLP_HID
#define NOUT      512      // IN_FEATS*HIDDEN
#define N_CLS     100000
#define TILE_E    64
#define N_TILES   (N_EDGES / TILE_E)   // 6250

typedef float  f32x4  __attribute__((ext_vector_type(4)));
typedef __bf16 bf16x8 __attribute__((ext_vector_type(8)));

__device__ __forceinline__ unsigned short f32_bf16(float f) {
    union { float f; uint32_t u; } c; c.f = f;
    uint32_t r = c.u + 0x7fffu + ((c.u >> 16) & 1u);
    return (unsigned short)(r >> 16);
}

// ---- prep: W2 [128,512] -> W2T bf16 [512,128]; W1 [16,128] -> W1T bf16 [128,32] (K padded) ----
__global__ void prep_weights(const float* __restrict__ w2, const float* __restrict__ w1,
                             unsigned short* __restrict__ w2t, unsigned short* __restrict__ w1t) {
    int tid = blockIdx.x * 256 + threadIdx.x;
    if (tid < NOUT * K1) {
        int n = tid >> 7, k = tid & 127;
        w2t[n * 128 + k] = f32_bf16(w2[k * 512 + n]);
    } else {
        int t = tid - NOUT * K1;            // [0, 4096)
        int n = t >> 5, k = t & 31;
        w1t[n * 32 + k] = (k < 16) ? f32_bf16(w1[k * 128 + n]) : (unsigned short)0;
    }
}

__global__ void zero_f32v4(float4* __restrict__ p, int n4) {
    int i = blockIdx.x * 256 + threadIdx.x;
    if (i < n4) { float4 z = {0.f, 0.f, 0.f, 0.f}; p[i] = z; }
}

// ---- fused: edge MLP (MFMA, swapped operands) + per-edge matvec + scatter-add ----
// wave w owns output-column chunk w (128 cols of 512). B streamed from L2, never resident.
// VGPR budget ~110: aF 32 + msgv 16 + xr 8 + acc 8 + bw 16 + misc.
__global__ __launch_bounds__(256) void fused_msg(
    const float* __restrict__ nf, const float* __restrict__ ef,
    const int* __restrict__ src, const int* __restrict__ dst,
    const unsigned short* __restrict__ w1t, const float* __restrict__ b1,
    const unsigned short* __restrict__ w2t, const float* __restrict__ b2,
    float* __restrict__ agg, float* __restrict__ deg)
{
    __shared__ __align__(16) unsigned short sW1T[128 * 32];   // 8KB, swizzled k ^= (n&3)<<3
    __shared__ __align__(16) unsigned short sAef[64 * 32];    // 4KB, swizzled k ^= (e&3)<<3
    __shared__ __align__(16) unsigned short sA[64 * 128];     // 16KB relu1, swizzled n ^= (e&7)<<3
    __shared__ __align__(16) float sX[64 * 20];               // 5KB, pad-20 for bank spread
    __shared__ __align__(16) float sPart[64 * 32];            // 8KB, swizzled h ^= (e&7)<<2
    __shared__ float sB1[128];
    __shared__ float sB2[512];
    __shared__ int   sSrc[64], sDst[64];

    const int tid  = threadIdx.x;
    const int e0   = blockIdx.x * TILE_E;
    const int lane = tid & 63;
    const int w    = tid >> 6;      // wave = output-column chunk
    const int l15  = lane & 15;
    const int lg   = lane >> 4;     // 0..3

    // ---------- phase 0: stage block-shared data ----------
    if (tid < 64)  { sSrc[tid] = src[e0 + tid]; sDst[tid] = dst[e0 + tid]; }
    if (tid < 128) sB1[tid] = b1[tid];
    sB2[tid] = b2[tid]; sB2[tid + 256] = b2[tid + 256];
    #pragma unroll
    for (int p = 0; p < 2; ++p) {
        int idx = p * 2048 + tid * 8;
        int n = idx >> 5, k0 = idx & 31;
        uint4 v = *reinterpret_cast<const uint4*>(&w1t[idx]);
        *reinterpret_cast<uint4*>(&sW1T[n * 32 + (k0 ^ ((n & 3) << 3))]) = v;
    }
    {
        int idx = tid * 8;
        int e = idx >> 5, k0 = idx & 31;
        unsigned short tmp[8];
        if (k0 < 16) {
            float4 f0 = *reinterpret_cast<const float4*>(&ef[(e0 + e) * 16 + k0]);
            float4 f1 = *reinterpret_cast<const float4*>(&ef[(e0 + e) * 16 + k0 + 4]);
            tmp[0] = f32_bf16(f0.x); tmp[1] = f32_bf16(f0.y); tmp[2] = f32_bf16(f0.z); tmp[3] = f32_bf16(f0.w);
            tmp[4] = f32_bf16(f1.x); tmp[5] = f32_bf16(f1.y); tmp[6] = f32_bf16(f1.z); tmp[7] = f32_bf16(f1.w);
        } else {
            #pragma unroll
            for (int j = 0; j < 8; ++j) tmp[j] = 0;
        }
        *reinterpret_cast<uint4*>(&sAef[e * 32 + (k0 ^ ((e & 3) << 3))]) = *reinterpret_cast<const uint4*>(tmp);
    }
    {   // zero sPart (2048 floats)
        float4 z = {0.f, 0.f, 0.f, 0.f};
        *reinterpret_cast<float4*>(&sPart[tid * 4]) = z;
        *reinterpret_cast<float4*>(&sPart[1024 + tid * 4]) = z;
    }
    __syncthreads();

    // ---------- phase 1: gather src feats, deg, layer-1 MFMA (swapped) ----------
    {
        int e = tid >> 2, q = tid & 3;
        float4 v = *reinterpret_cast<const float4*>(&nf[sSrc[e] * 16 + q * 4]);
        *reinterpret_cast<float4*>(&sX[e * 20 + q * 4]) = v;
    }
    if (tid < 64) atomicAdd(&deg[sDst[tid]], 1.0f);
    {
        int e = w * 16 + l15;                 // this wave's relu1 rows
        int sw8 = (l15 & 7) << 3;
        bf16x8 aef = *reinterpret_cast<const bf16x8*>(&sAef[e % 64 * 32 + ((lg * 8) ^ ((e & 3) << 3))]);
        #pragma unroll
        for (int f = 0; f < 8; ++f) {
            int n = f * 16 + l15;
            bf16x8 bw1 = *reinterpret_cast<const bf16x8*>(&sW1T[n * 32 + ((lg * 8) ^ ((n & 3) << 3))]);
            f32x4 c = *reinterpret_cast<const f32x4*>(&sB1[f * 16 + lg * 4]);
            c = __builtin_amdgcn_mfma_f32_16x16x32_bf16(bw1, aef, c, 0, 0, 0);
            // D[n][e]: col(l15)=e, row(lg*4+r)=n -> 4 consecutive n for this lane
            uint32_t u0 = (uint32_t)f32_bf16(fmaxf(c[0], 0.f)) | ((uint32_t)f32_bf16(fmaxf(c[1], 0.f)) << 16);
            uint32_t u1 = (uint32_t)f32_bf16(fmaxf(c[2], 0.f)) | ((uint32_t)f32_bf16(fmaxf(c[3], 0.f)) << 16);
            uint2 pk = { u0, u1 };
            int n0 = f * 16 + lg * 4;
            *reinterpret_cast<uint2*>(&sA[e * 128 + (n0 ^ sw8)]) = pk;
        }
    }
    __syncthreads();

    // ---------- phase 2: layer-2 (B from L2, swapped operands), msg partials ----------
    {
        int sw8 = (l15 & 7) << 3;
        #pragma unroll
        for (int eh = 0; eh < 2; ++eh) {          // e-halves: rows eh*32 .. eh*32+31
            bf16x8 aF[2][4];
            float  xa[2][4];
            #pragma unroll
            for (int et = 0; et < 2; ++et) {
                int e = (eh * 2 + et) * 16 + l15;
                #pragma unroll
                for (int kb = 0; kb < 4; ++kb)
                    aF[et][kb] = *reinterpret_cast<const bf16x8*>(
                        &sA[e * 128 + ((kb * 32 + lg * 8) ^ sw8)]);
                float4 xv = *reinterpret_cast<const float4*>(&sX[e * 20 + w * 4]);
                xa[et][0] = xv.x; xa[et][1] = xv.y; xa[et][2] = xv.z; xa[et][3] = xv.w;
            }
            float msgv[2][8];
            #pragma unroll
            for (int et = 0; et < 2; ++et)
                #pragma unroll
                for (int q = 0; q < 8; ++q) msgv[et][q] = 0.f;

            #pragma unroll
            for (int f = 0; f < 8; ++f) {
                bf16x8 bw[4];
                #pragma unroll
                for (int kb = 0; kb < 4; ++kb)
                    bw[kb] = *reinterpret_cast<const bf16x8*>(
                        &w2t[(w * 128 + f * 16 + l15) * 128 + kb * 32 + lg * 8]);
                f32x4 b2q = *reinterpret_cast<const f32x4*>(&sB2[w * 128 + f * 16 + lg * 4]);
                f32x4 a0 = b2q, a1 = b2q;
                #pragma unroll
                for (int kb = 0; kb < 4; ++kb) {
                    a0 = __builtin_amdgcn_mfma_f32_16x16x32_bf16(bw[kb], aF[0][kb], a0, 0, 0, 0);
                    a1 = __builtin_amdgcn_mfma_f32_16x16x32_bf16(bw[kb], aF[1][kb], a1, 0, 0, 0);
                }
                // D[n][e]: lane holds e=et*16+l15 (lane-local!), n = w*128+f*16+lg*4+r
                // i = w*4 + (f>>1), h = (f&1)*16 + lg*4 + r
                const int half = f & 1;
                #pragma unroll
                for (int r = 0; r < 4; ++r) {
                    msgv[0][half * 4 + r] += xa[0][f >> 1] * a0[r];
                    msgv[1][half * 4 + r] += xa[1][f >> 1] * a1[r];
                }
            }
            // LDS reduce across waves (i-ranges); r-order rotated by lg for full-bank spread
            #pragma unroll
            for (int et = 0; et < 2; ++et) {
                int e = (eh * 2 + et) * 16 + l15;
                int swp = (l15 & 7) << 2;
                #pragma unroll
                for (int half = 0; half < 2; ++half)
                    #pragma unroll
                    for (int rr = 0; rr < 4; ++rr) {
                        int r  = (rr + lg) & 3;
                        int hh = half * 16 + lg * 4 + r;
                        atomicAdd(&sPart[e * 32 + (hh ^ swp)], msgv[et][half * 4 + r]);
                    }
            }
        }
    }
    __syncthreads();

    // ---------- phase 3: scatter to agg ----------
    #pragma unroll
    for (int k = 0; k < 8; ++k) {
        int idx = tid + k * 256;
        int e = idx >> 5, hh = idx & 31;
        float val = sPart[e * 32 + (hh ^ ((e & 7) << 2))];
        atomicAdd(&agg[sDst[e] * 32 + hh], val);
    }
}

// ---- h = relu(agg/max(deg,1) + conv_b), float4 ----
__global__ void finalize_h(const float* __restrict__ agg, const float* __restrict__ deg,
                           const float* __restrict__ conv_b, float* __restrict__ h) {
    int t = blockIdx.x * 256 + threadIdx.x;
    if (t >= N_NODES * 8) return;
    int v = t >> 3, f0 = (t & 7) * 4;
    float d = fmaxf(deg[v], 1.0f);
    float4 a  = *reinterpret_cast<const float4*>(&agg[t * 4]);
    float4 cb = *reinterpret_cast<const float4*>(&conv_b[f0]);
    float4 o;
    o.x = fmaxf(a.x / d + cb.x, 0.f);
    o.y = fmaxf(a.y / d + cb.y, 0.f);
    o.z = fmaxf(a.z / d + cb.z, 0.f);
    o.w = fmaxf(a.w / d + cb.w, 0.f);
    *reinterpret_cast<float4*>(&h[t * 4]) = o;
}

// ---- classifier: 32 edges per 256-thread block ----
__global__ __launch_bounds__(256) void classifier(
    const float* __restrict__ h, const float* __restrict__ ef,
    const int* __restrict__ src, const int* __restrict__ dst, const int* __restrict__ eidx,
    const float* __restrict__ w1, const float* __restrict__ b1,
    const float* __restrict__ w2, const float* __restrict__ b2, float* __restrict__ out)
{
    __shared__ float sIn[32][84];
    __shared__ float sW1[80 * 32];
    __shared__ float sHid[32][36];
    __shared__ int   sE[32 * 3];
    int tid = threadIdx.x;
    int eb  = blockIdx.x * 32;

    for (int i = tid; i < 640; i += 256)
        *reinterpret_cast<float4*>(&sW1[i * 4]) = *reinterpret_cast<const float4*>(&w1[i * 4]);
    if (tid < 32) {
        int ei = eidx[eb + tid];
        sE[tid * 3 + 0] = ei;
        sE[tid * 3 + 1] = src[ei];
        sE[tid * 3 + 2] = dst[ei];
    }
    __syncthreads();
    {
        int e = tid >> 3, l8 = tid & 7;
        int ei = sE[e * 3 + 0], sn = sE[e * 3 + 1], dn = sE[e * 3 + 2];
        #pragma unroll
        for (int j = 0; j < 10; ++j) {
            int c = l8 + j * 8;
            float v;
            if (c < 32)      v = h[sn * 32 + c];
            else if (c < 64) v = h[dn * 32 + (c - 32)];
            else             v = ef[ei * 16 + (c - 64)];
            sIn[e][c] = v;
        }
    }
    __syncthreads();
    {
        int e = tid >> 3, j0 = (tid & 7) * 4;
        float4 acc = *reinterpret_cast<const float4*>(&b1[j0]);
        #pragma unroll 8
        for (int k = 0; k < 80; ++k) {
            float x = sIn[e][k];
            float4 wv = *reinterpret_cast<const float4*>(&sW1[k * 32 + j0]);
            acc.x += x * wv.x; acc.y += x * wv.y; acc.z += x * wv.z; acc.w += x * wv.w;
        }
        sHid[e][j0 + 0] = fmaxf(acc.x, 0.f);
        sHid[e][j0 + 1] = fmaxf(acc.y, 0.f);
        sHid[e][j0 + 2] = fmaxf(acc.z, 0.f);
        sHid[e][j0 + 3] = fmaxf(acc.w, 0.f);
    }
    __syncthreads();
    if (tid < 64) {
        int e = tid >> 1, o = tid & 1;
        float acc = b2[o];
        #pragma unroll
        for (int j = 0; j < 32; ++j) acc += sHid[e][j] * w2[j * 2 + o];
        out[(eb + e) * 2 + o] = acc;
    }
}

extern "C" void kernel_launch(void* const* d_in, const int* in_sizes, int n_in,
                              void* d_out, int out_size, void* d_ws, size_t ws_size,
                              hipStream_t stream) {
    const float* nf     = (const float*)d_in[0];
    const float* ef     = (const float*)d_in[1];
    const int*   src    = (const int*)d_in[2];
    const int*   dst    = (const int*)d_in[3];
    const int*   eidx   = (const int*)d_in[4];
    const float* en_w1  = (const float*)d_in[5];
    const float* en_b1  = (const float*)d_in[6];
    const float* en_w2  = (const float*)d_in[7];
    const float* en_b2  = (const float*)d_in[8];
    const float* conv_b = (const float*)d_in[9];
    const float* cls_w1 = (const float*)d_in[10];
    const float* cls_b1 = (const float*)d_in[11];
    const float* cls_w2 = (const float*)d_in[12];
    const float* cls_b2 = (const float*)d_in[13];
    float* out = (float*)d_out;

    char* ws = (char*)d_ws;
    unsigned short* w2t = (unsigned short*)(ws);               // 131072 B
    unsigned short* w1t = (unsigned short*)(ws + 131072);      // 8192 B
    float* agg = (float*)(ws + 139264);                        // 6,400,000 B
    float* deg = (float*)(ws + 139264 + 6400000);              // 200,000 B
    float* h   = (float*)(ws + 139264 + 6600000);              // 6,400,000 B

    // zero agg+deg (contiguous 1,650,000 floats = 412,500 float4)
    zero_f32v4<<<(412500 + 255) / 256, 256, 0, stream>>>((float4*)agg, 412500);
    prep_weights<<<(NOUT * K1 + 4096) / 256, 256, 0, stream>>>(en_w2, en_w1, w2t, w1t);
    fused_msg<<<N_TILES, 256, 0, stream>>>(nf, ef, src, dst, w1t, en_b1, w2t, en_b2, agg, deg);
    finalize_h<<<(N_NODES * 8 + 255) / 256, 256, 0, stream>>>(agg, deg, conv_b, h);
    classifier<<<N_CLS / 32, 256, 0, stream>>>(h, ef, src, dst, eidx, cls_w1, cls_b1, cls_w2, cls_b2, out);
}